// Round 1
// baseline (742.264 us; speedup 1.0000x reference)
//
#include <hip/hip_runtime.h>

// ---------------------------------------------------------------------------
// RNNModel: 3-layer tanh RNN (B=128, T=512, IN=768, H=64) + FC(64->1)
// Kernel 1: fp32 GEMM  pre0[65536][64] = x[65536][768] @ W_ih0^T + (b_ih0+b_hh0)
// Kernel 2: fused 3-layer recurrence, layer-pipelined across timesteps,
//           one block per batch element, + final FC.
// ---------------------------------------------------------------------------

__device__ __forceinline__ float tanh_fast(float x) {
    // tanh(x) = 1 - 2/(exp(2x)+1); v_exp_f32 + v_rcp_f32, ~1e-6 abs err.
    float e = __expf(2.0f * x);
    return 1.0f - 2.0f * __builtin_amdgcn_rcpf(e + 1.0f);
}

// ---------------------------------------------------------------------------
// GEMM: block computes 128 rows x 64 cols. 4 waves; wave w owns rows w*32..+31,
// lane = col. B (W_ih0 tile) read per-lane from LDS, A rows broadcast (b128).
// K chunked by 32 with register prefetch.
// ---------------------------------------------------------------------------
__global__ __launch_bounds__(256) void gemm_pre0(
    const float* __restrict__ x,    // [65536][768]
    const float* __restrict__ Wih,  // [64][768]
    const float* __restrict__ bih, const float* __restrict__ bhh,
    float* __restrict__ pre0)       // [65536][64]
{
    __shared__ float As[32][132];   // [k][row], padded (132: conflict-breaking)
    __shared__ float Bs[32][65];    // [k][col], padded

    const int tid = threadIdx.x;
    const int wave = tid >> 6;
    const int lane = tid & 63;
    const int rowBase = blockIdx.x * 128;
    const int waveRow = wave * 32;

    float acc[32];
#pragma unroll
    for (int r = 0; r < 32; ++r) acc[r] = 0.0f;

    float4 aReg[4];
    float4 bReg[2];

    // prologue: load chunk 0 into regs
#pragma unroll
    for (int jj = 0; jj < 4; ++jj) {
        int i = tid + 256 * jj;
        int row = i >> 3, k4 = i & 7;
        aReg[jj] = *(const float4*)&x[(size_t)(rowBase + row) * 768 + 4 * k4];
    }
#pragma unroll
    for (int jj = 0; jj < 2; ++jj) {
        int i = tid + 256 * jj;
        int h = i >> 3, k4 = i & 7;
        bReg[jj] = *(const float4*)&Wih[h * 768 + 4 * k4];
    }

    for (int c = 0; c < 24; ++c) {
        // stage regs -> LDS (transposed)
#pragma unroll
        for (int jj = 0; jj < 4; ++jj) {
            int i = tid + 256 * jj;
            int row = i >> 3, k4 = (i & 7) * 4;
            As[k4 + 0][row] = aReg[jj].x;
            As[k4 + 1][row] = aReg[jj].y;
            As[k4 + 2][row] = aReg[jj].z;
            As[k4 + 3][row] = aReg[jj].w;
        }
#pragma unroll
        for (int jj = 0; jj < 2; ++jj) {
            int i = tid + 256 * jj;
            int h = i >> 3, k4 = (i & 7) * 4;
            Bs[k4 + 0][h] = bReg[jj].x;
            Bs[k4 + 1][h] = bReg[jj].y;
            Bs[k4 + 2][h] = bReg[jj].z;
            Bs[k4 + 3][h] = bReg[jj].w;
        }
        __syncthreads();

        // prefetch next chunk while computing this one
        if (c + 1 < 24) {
            const int kb = (c + 1) * 32;
#pragma unroll
            for (int jj = 0; jj < 4; ++jj) {
                int i = tid + 256 * jj;
                int row = i >> 3, k4 = i & 7;
                aReg[jj] = *(const float4*)&x[(size_t)(rowBase + row) * 768 + kb + 4 * k4];
            }
#pragma unroll
            for (int jj = 0; jj < 2; ++jj) {
                int i = tid + 256 * jj;
                int h = i >> 3, k4 = i & 7;
                bReg[jj] = *(const float4*)&Wih[h * 768 + kb + 4 * k4];
            }
        }

#pragma unroll 8
        for (int k = 0; k < 32; ++k) {
            float bv = Bs[k][lane];
#pragma unroll
            for (int m = 0; m < 8; ++m) {
                float4 av = *(const float4*)&As[k][waveRow + 4 * m];  // broadcast
                acc[4 * m + 0] += av.x * bv;
                acc[4 * m + 1] += av.y * bv;
                acc[4 * m + 2] += av.z * bv;
                acc[4 * m + 3] += av.w * bv;
            }
        }
        __syncthreads();
    }

    const float bias = bih[lane] + bhh[lane];
#pragma unroll
    for (int r = 0; r < 32; ++r) {
        int row = rowBase + waveRow + r;
        pre0[(size_t)row * 64 + lane] = acc[r] + bias;
    }
}

// ---------------------------------------------------------------------------
// Fused recurrence. Block = batch element b; 768 threads = 3 groups of 256.
// Group g computes layer g at time t-g. hr[] = 6 parity-slotted h vectors.
// pre0 staged via double-buffered LDS chunks of 16 steps (register prefetch).
// ---------------------------------------------------------------------------
__global__ __launch_bounds__(768) void rnn_fused(
    const float* __restrict__ pre0,  // [128*512][64]
    const float* __restrict__ Whh0,
    const float* __restrict__ Wih1, const float* __restrict__ Whh1,
    const float* __restrict__ bih1, const float* __restrict__ bhh1,
    const float* __restrict__ Wih2, const float* __restrict__ Whh2,
    const float* __restrict__ bih2, const float* __restrict__ bhh2,
    const float* __restrict__ fcw, const float* __restrict__ fcb,
    float* __restrict__ out)
{
    const int tid  = threadIdx.x;
    const int g    = tid >> 8;       // layer group 0..2
    const int t256 = tid & 255;
    const int j    = t256 >> 2;      // output hidden unit 0..63
    const int q    = t256 & 3;       // k-quarter 0..3
    const int b    = blockIdx.x;

    __shared__ float hr[6][64];      // [0..1]=h0 parity, [2..3]=h1, [4..5]=h2
    __shared__ float preS[2][1024];  // 16 steps x 64, double-buffered

    // --- per-thread weight fragments (rows j, k-quarter q) ---
    float wA[16], wB[16];
    float bias = 0.0f;
    {
        const float* WA = (g == 0) ? Whh0 : ((g == 1) ? Wih1 : Wih2);
#pragma unroll
        for (int i = 0; i < 16; i += 4)
            *(float4*)&wA[i] = *(const float4*)&WA[j * 64 + q * 16 + i];
        if (g > 0) {
            const float* WB = (g == 1) ? Whh1 : Whh2;
#pragma unroll
            for (int i = 0; i < 16; i += 4)
                *(float4*)&wB[i] = *(const float4*)&WB[j * 64 + q * 16 + i];
            bias = (g == 1) ? (bih1[j] + bhh1[j]) : (bih2[j] + bhh2[j]);
        } else {
#pragma unroll
            for (int i = 0; i < 16; ++i) wB[i] = 0.0f;
        }
    }

    // --- init: group0 stages chunk 0; groups 1/2 zero the h slots ---
    const int sl = t256 >> 4;   // step_local 0..15
    const int f4 = t256 & 15;   // float4 index within step
    float4 pReg = make_float4(0.f, 0.f, 0.f, 0.f);
    const size_t pbase = (size_t)b * 512 * 64;
    if (g == 0) {
        pReg = *(const float4*)&pre0[pbase + (size_t)sl * 64 + f4 * 4];
        *(float4*)&preS[0][sl * 64 + f4 * 4] = pReg;
    } else {
        int z = tid - 256;
        if (z < 384) ((float*)hr)[z] = 0.0f;
    }
    __syncthreads();

    for (int t = 0; t < 514; ++t) {
        const int cl = t & 15;
        const int cc = t >> 4;

        // group0: issue global prefetch of next pre0 chunk at chunk start
        if (g == 0 && t < 512 && cl == 0 && (cc + 1) < 32) {
            pReg = *(const float4*)&pre0[pbase + (size_t)((cc + 1) * 16 + sl) * 64 + f4 * 4];
        }

        float hNew = 0.0f;
        bool active = false;
        int outSlot = 0;

        if (g == 0) {
            active = (t < 512);
            if (active) {
                const float* rc = hr[(t + 1) & 1];      // h0[t-1]
                float a0 = 0.f, a1 = 0.f;
#pragma unroll
                for (int i = 0; i < 16; i += 4) {
                    float4 h4 = *(const float4*)&rc[q * 16 + i];
                    a0 += wA[i + 0] * h4.x;
                    a1 += wA[i + 1] * h4.y;
                    a0 += wA[i + 2] * h4.z;
                    a1 += wA[i + 3] * h4.w;
                }
                float s = a0 + a1;
                s += __shfl_xor(s, 1, 64);
                s += __shfl_xor(s, 2, 64);
                float val = s + preS[cc & 1][cl * 64 + j];
                hNew = tanh_fast(val);
                outSlot = t & 1;
            }
        } else if (g == 1) {
            int ss = t - 1;
            active = (ss >= 0 && ss < 512);
            if (active) {
                const float* in = hr[ss & 1];              // h0[ss]
                const float* rc = hr[2 + ((ss + 1) & 1)];  // h1[ss-1]
                float a0 = 0.f, a1 = 0.f;
#pragma unroll
                for (int i = 0; i < 16; i += 4) {
                    float4 x4 = *(const float4*)&in[q * 16 + i];
                    float4 h4 = *(const float4*)&rc[q * 16 + i];
                    a0 += wA[i + 0] * x4.x;  a1 += wB[i + 0] * h4.x;
                    a0 += wA[i + 1] * x4.y;  a1 += wB[i + 1] * h4.y;
                    a0 += wA[i + 2] * x4.z;  a1 += wB[i + 2] * h4.z;
                    a0 += wA[i + 3] * x4.w;  a1 += wB[i + 3] * h4.w;
                }
                float s = a0 + a1;
                s += __shfl_xor(s, 1, 64);
                s += __shfl_xor(s, 2, 64);
                hNew = tanh_fast(s + bias);
                outSlot = 2 + (ss & 1);
            }
        } else {
            int uu = t - 2;
            active = (uu >= 0 && uu < 512);
            if (active) {
                const float* in = hr[2 + (uu & 1)];        // h1[uu]
                const float* rc = hr[4 + ((uu + 1) & 1)];  // h2[uu-1]
                float a0 = 0.f, a1 = 0.f;
#pragma unroll
                for (int i = 0; i < 16; i += 4) {
                    float4 x4 = *(const float4*)&in[q * 16 + i];
                    float4 h4 = *(const float4*)&rc[q * 16 + i];
                    a0 += wA[i + 0] * x4.x;  a1 += wB[i + 0] * h4.x;
                    a0 += wA[i + 1] * x4.y;  a1 += wB[i + 1] * h4.y;
                    a0 += wA[i + 2] * x4.z;  a1 += wB[i + 2] * h4.z;
                    a0 += wA[i + 3] * x4.w;  a1 += wB[i + 3] * h4.w;
                }
                float s = a0 + a1;
                s += __shfl_xor(s, 1, 64);
                s += __shfl_xor(s, 2, 64);
                hNew = tanh_fast(s + bias);
                outSlot = 4 + (uu & 1);
            }
        }

        if (active && q == 0) hr[outSlot][j] = hNew;

        // group0: commit prefetched chunk into the other preS buffer
        if (g == 0 && cl == 15 && t < 511) {
            *(float4*)&preS[(cc + 1) & 1][sl * 64 + f4 * 4] = pReg;
        }
        __syncthreads();
    }

    // FC epilogue: h2[511] lives in hr[5] (parity 511&1 = 1)
    if (tid < 64) {
        float v = hr[5][tid] * fcw[tid];
#pragma unroll
        for (int m = 1; m < 64; m <<= 1) v += __shfl_xor(v, m, 64);
        if (tid == 0) out[b] = v + fcb[0];
    }
}

extern "C" void kernel_launch(void* const* d_in, const int* in_sizes, int n_in,
                              void* d_out, int out_size, void* d_ws, size_t ws_size,
                              hipStream_t stream) {
    const float* x    = (const float*)d_in[0];
    // d_in[1] = fixation_num (unused by the reference computation)
    const float* Wih0 = (const float*)d_in[2];
    const float* Whh0 = (const float*)d_in[3];
    const float* bih0 = (const float*)d_in[4];
    const float* bhh0 = (const float*)d_in[5];
    const float* Wih1 = (const float*)d_in[6];
    const float* Whh1 = (const float*)d_in[7];
    const float* bih1 = (const float*)d_in[8];
    const float* bhh1 = (const float*)d_in[9];
    const float* Wih2 = (const float*)d_in[10];
    const float* Whh2 = (const float*)d_in[11];
    const float* bih2 = (const float*)d_in[12];
    const float* bhh2 = (const float*)d_in[13];
    const float* fcw  = (const float*)d_in[14];
    const float* fcb  = (const float*)d_in[15];
    float* out  = (float*)d_out;
    float* pre0 = (float*)d_ws;   // 65536*64 floats = 16.78 MB

    gemm_pre0<<<512, 256, 0, stream>>>(x, Wih0, bih0, bhh0, pre0);
    rnn_fused<<<128, 768, 0, stream>>>(pre0, Whh0, Wih1, Whh1, bih1, bhh1,
                                       Wih2, Whh2, bih2, bhh2, fcw, fcb, out);
}

// Round 2
// 663.303 us; speedup vs baseline: 1.1190x; 1.1190x over previous
//
#include <hip/hip_runtime.h>

// ---------------------------------------------------------------------------
// RNNModel: 3-layer tanh RNN (B=128, T=512, IN=768, H=64) + FC(64->1)
// Kernel 1: fp32 GEMM  pre0[65536][64] = x[65536][768] @ W_ih0^T + (b_ih0+b_hh0)
//           8x4 register tile per thread (3 LDS b128 per 32 fma).
// Kernel 2: fused recurrence: 3 waves/block (wave = layer, pipelined in t),
//           weights register-resident per lane, h exchanged via LDS broadcast.
// ---------------------------------------------------------------------------

__device__ __forceinline__ float tanh_fast(float x) {
    float e = __expf(2.0f * x);
    return 1.0f - 2.0f * __builtin_amdgcn_rcpf(e + 1.0f);
}

// ---------------------------------------------------------------------------
// GEMM: block tile M=128 x N=64, K-chunk 32. 256 threads, each 8 rows x 4 cols.
// ---------------------------------------------------------------------------
__global__ __launch_bounds__(256) void gemm_pre0(
    const float* __restrict__ x,    // [65536][768]
    const float* __restrict__ Wih,  // [64][768]
    const float* __restrict__ bih, const float* __restrict__ bhh,
    float* __restrict__ pre0)       // [65536][64]
{
    __shared__ float As[32][132];   // [k][row]
    __shared__ float Bs[32][68];    // [k][col]

    const int tid = threadIdx.x;
    const int tx = tid & 15;        // col group: cols tx*4..+4
    const int ty = tid >> 4;        // row group: rows ty*8..+8
    const int rowBase = blockIdx.x * 128;

    float acc[8][4];
#pragma unroll
    for (int r = 0; r < 8; ++r)
#pragma unroll
        for (int c = 0; c < 4; ++c) acc[r][c] = 0.0f;

    float4 aReg[4];   // A stage: 128 rows x 32 k = 1024 f4 / 256 thr
    float4 bReg[2];   // B stage: 64 rows x 32 k = 512 f4 / 256 thr

    // prologue: chunk 0 -> regs  (i>>3 = row, (i&7)*4 = k offset; 128B/row)
#pragma unroll
    for (int jj = 0; jj < 4; ++jj) {
        int i = tid + 256 * jj;
        aReg[jj] = *(const float4*)&x[(size_t)(rowBase + (i >> 3)) * 768 + 4 * (i & 7)];
    }
#pragma unroll
    for (int jj = 0; jj < 2; ++jj) {
        int i = tid + 256 * jj;
        bReg[jj] = *(const float4*)&Wih[(i >> 3) * 768 + 4 * (i & 7)];
    }

    for (int c = 0; c < 24; ++c) {
        // stage regs -> LDS (k-major, transposed)
#pragma unroll
        for (int jj = 0; jj < 4; ++jj) {
            int i = tid + 256 * jj;
            int r = i >> 3, k4 = (i & 7) * 4;
            As[k4 + 0][r] = aReg[jj].x;
            As[k4 + 1][r] = aReg[jj].y;
            As[k4 + 2][r] = aReg[jj].z;
            As[k4 + 3][r] = aReg[jj].w;
        }
#pragma unroll
        for (int jj = 0; jj < 2; ++jj) {
            int i = tid + 256 * jj;
            int h = i >> 3, k4 = (i & 7) * 4;
            Bs[k4 + 0][h] = bReg[jj].x;
            Bs[k4 + 1][h] = bReg[jj].y;
            Bs[k4 + 2][h] = bReg[jj].z;
            Bs[k4 + 3][h] = bReg[jj].w;
        }
        __syncthreads();

        if (c + 1 < 24) {
            const int kb = (c + 1) * 32;
#pragma unroll
            for (int jj = 0; jj < 4; ++jj) {
                int i = tid + 256 * jj;
                aReg[jj] = *(const float4*)&x[(size_t)(rowBase + (i >> 3)) * 768 + kb + 4 * (i & 7)];
            }
#pragma unroll
            for (int jj = 0; jj < 2; ++jj) {
                int i = tid + 256 * jj;
                bReg[jj] = *(const float4*)&Wih[(i >> 3) * 768 + kb + 4 * (i & 7)];
            }
        }

#pragma unroll
        for (int k = 0; k < 32; ++k) {
            float4 a0 = *(const float4*)&As[k][ty * 8];      // broadcast (16 lanes)
            float4 a1 = *(const float4*)&As[k][ty * 8 + 4];
            float4 bv = *(const float4*)&Bs[k][tx * 4];      // broadcast (4 lanes)
            float ar[8] = {a0.x, a0.y, a0.z, a0.w, a1.x, a1.y, a1.z, a1.w};
            float bc[4] = {bv.x, bv.y, bv.z, bv.w};
#pragma unroll
            for (int r = 0; r < 8; ++r)
#pragma unroll
                for (int cc = 0; cc < 4; ++cc)
                    acc[r][cc] += ar[r] * bc[cc];
        }
        __syncthreads();
    }

    float4 bias = make_float4(bih[tx * 4 + 0] + bhh[tx * 4 + 0],
                              bih[tx * 4 + 1] + bhh[tx * 4 + 1],
                              bih[tx * 4 + 2] + bhh[tx * 4 + 2],
                              bih[tx * 4 + 3] + bhh[tx * 4 + 3]);
#pragma unroll
    for (int r = 0; r < 8; ++r) {
        int row = rowBase + ty * 8 + r;
        float4 v = make_float4(acc[r][0] + bias.x, acc[r][1] + bias.y,
                               acc[r][2] + bias.z, acc[r][3] + bias.w);
        *(float4*)&pre0[(size_t)row * 64 + tx * 4] = v;
    }
}

// ---------------------------------------------------------------------------
// Recurrence: block = batch element, 3 waves (wave g = layer g at time t-g).
// Lane j owns output unit j; weight rows in VGPRs; h via LDS broadcast.
// ---------------------------------------------------------------------------
__global__ __launch_bounds__(192) void rnn_fused(
    const float* __restrict__ pre0,  // [128*512][64], biases folded in
    const float* __restrict__ Whh0,
    const float* __restrict__ Wih1, const float* __restrict__ Whh1,
    const float* __restrict__ bih1, const float* __restrict__ bhh1,
    const float* __restrict__ Wih2, const float* __restrict__ Whh2,
    const float* __restrict__ bih2, const float* __restrict__ bhh2,
    const float* __restrict__ fcw, const float* __restrict__ fcb,
    float* __restrict__ out)
{
    const int tid = threadIdx.x;
    const int g   = tid >> 6;        // layer 0..2
    const int j   = tid & 63;        // output unit
    const int b   = blockIdx.x;

    __shared__ float hs[6][64];      // [2*layer + parity][unit]

    // register-resident weight rows
    const float* WA = (g == 0) ? Whh0 : ((g == 1) ? Wih1 : Wih2);
    const float* WB = (g == 0) ? Whh0 : ((g == 1) ? Whh1 : Whh2);  // g0: dummy
    float wA[64], wB[64];
#pragma unroll
    for (int i = 0; i < 64; i += 4) {
        *(float4*)&wA[i] = *(const float4*)&WA[j * 64 + i];
        *(float4*)&wB[i] = *(const float4*)&WB[j * 64 + i];
    }
    const float bias = (g == 0) ? 0.0f
                     : ((g == 1) ? (bih1[j] + bhh1[j]) : (bih2[j] + bhh2[j]));

    // zero parity slots (h[-1] = 0)
    ((float*)hs)[tid] = 0.0f;
    ((float*)hs)[tid + 192] = 0.0f;

    // pre0 rolling prefetch for wave 0
    const size_t pbase = (size_t)b * 32768;
    float p0 = 0.f, p1 = 0.f;
    if (g == 0) {
        p0 = pre0[pbase + j];
        p1 = pre0[pbase + 64 + j];
    }
    __syncthreads();

    float hLast = 0.0f;

    for (int i = 0; i < 514; ++i) {
        if (g == 0) {
            if (i < 512) {
                const float* rc = hs[(i + 1) & 1];   // h0[i-1]
                float a0 = 0.f, a1 = 0.f, a2 = 0.f, a3 = 0.f;
#pragma unroll
                for (int kk = 0; kk < 16; ++kk) {
                    float4 h4 = *(const float4*)&rc[4 * kk];
                    a0 += wA[4 * kk + 0] * h4.x;
                    a1 += wA[4 * kk + 1] * h4.y;
                    a2 += wA[4 * kk + 2] * h4.z;
                    a3 += wA[4 * kk + 3] * h4.w;
                }
                float hN = tanh_fast((a0 + a1) + (a2 + a3) + p0);
                hs[i & 1][j] = hN;
                p0 = p1;
                if (i + 2 < 512) p1 = pre0[pbase + (size_t)(i + 2) * 64 + j];
            }
        } else if (g == 1) {
            int t = i - 1;
            if (t >= 0 && t < 512) {
                const float* inx = hs[t & 1];            // h0[t]
                const float* rc  = hs[2 + ((t + 1) & 1)]; // h1[t-1]
                float a0 = 0.f, a1 = 0.f, a2 = 0.f, a3 = 0.f;
#pragma unroll
                for (int kk = 0; kk < 16; ++kk) {
                    float4 x4 = *(const float4*)&inx[4 * kk];
                    float4 h4 = *(const float4*)&rc[4 * kk];
                    a0 += wA[4 * kk + 0] * x4.x;  a1 += wB[4 * kk + 0] * h4.x;
                    a2 += wA[4 * kk + 1] * x4.y;  a3 += wB[4 * kk + 1] * h4.y;
                    a0 += wA[4 * kk + 2] * x4.z;  a1 += wB[4 * kk + 2] * h4.z;
                    a2 += wA[4 * kk + 3] * x4.w;  a3 += wB[4 * kk + 3] * h4.w;
                }
                float hN = tanh_fast((a0 + a1) + (a2 + a3) + bias);
                hs[2 + (t & 1)][j] = hN;
            }
        } else {
            int t = i - 2;
            if (t >= 0 && t < 512) {
                const float* inx = hs[2 + (t & 1)];       // h1[t]
                const float* rc  = hs[4 + ((t + 1) & 1)]; // h2[t-1]
                float a0 = 0.f, a1 = 0.f, a2 = 0.f, a3 = 0.f;
#pragma unroll
                for (int kk = 0; kk < 16; ++kk) {
                    float4 x4 = *(const float4*)&inx[4 * kk];
                    float4 h4 = *(const float4*)&rc[4 * kk];
                    a0 += wA[4 * kk + 0] * x4.x;  a1 += wB[4 * kk + 0] * h4.x;
                    a2 += wA[4 * kk + 1] * x4.y;  a3 += wB[4 * kk + 1] * h4.y;
                    a0 += wA[4 * kk + 2] * x4.z;  a1 += wB[4 * kk + 2] * h4.z;
                    a2 += wA[4 * kk + 3] * x4.w;  a3 += wB[4 * kk + 3] * h4.w;
                }
                float hN = tanh_fast((a0 + a1) + (a2 + a3) + bias);
                hs[4 + (t & 1)][j] = hN;
                if (t == 511) hLast = hN;
            }
        }
        __syncthreads();
    }

    // FC epilogue on wave 2 (holds h2[511] in hLast)
    if (g == 2) {
        float v = hLast * fcw[j];
#pragma unroll
        for (int m = 1; m < 64; m <<= 1) v += __shfl_xor(v, m, 64);
        if (j == 0) out[b] = v + fcb[0];
    }
}

extern "C" void kernel_launch(void* const* d_in, const int* in_sizes, int n_in,
                              void* d_out, int out_size, void* d_ws, size_t ws_size,
                              hipStream_t stream) {
    const float* x    = (const float*)d_in[0];
    const float* Wih0 = (const float*)d_in[2];
    const float* Whh0 = (const float*)d_in[3];
    const float* bih0 = (const float*)d_in[4];
    const float* bhh0 = (const float*)d_in[5];
    const float* Wih1 = (const float*)d_in[6];
    const float* Whh1 = (const float*)d_in[7];
    const float* bih1 = (const float*)d_in[8];
    const float* bhh1 = (const float*)d_in[9];
    const float* Wih2 = (const float*)d_in[10];
    const float* Whh2 = (const float*)d_in[11];
    const float* bih2 = (const float*)d_in[12];
    const float* bhh2 = (const float*)d_in[13];
    const float* fcw  = (const float*)d_in[14];
    const float* fcb  = (const float*)d_in[15];
    float* out  = (float*)d_out;
    float* pre0 = (float*)d_ws;   // 16.78 MB

    gemm_pre0<<<512, 256, 0, stream>>>(x, Wih0, bih0, bhh0, pre0);
    rnn_fused<<<128, 192, 0, stream>>>(pre0, Whh0, Wih1, Whh1, bih1, bhh1,
                                       Wih2, Whh2, bih2, bhh2, fcw, fcb, out);
}

// Round 4
// 553.576 us; speedup vs baseline: 1.3409x; 1.1982x over previous
//
#include <hip/hip_runtime.h>

// ---------------------------------------------------------------------------
// RNNModel: 3-layer tanh RNN (B=128, T=512, IN=768, H=64) + FC(64->1)
// K1: f16-dot2 GEMM  pre0[65536][64] = x @ W_ih0^T + (b_ih0+b_hh0)   (fp32 out)
// K2: fused recurrence, 3 waves/block (wave=layer, pipelined in t),
//     f16 packed weights in VGPRs, f16 h exchange via LDS, v_dot2_f32_f16.
// ---------------------------------------------------------------------------

typedef __fp16 h2_t __attribute__((ext_vector_type(2)));

union F4H { float4 f; h2_t h[4]; };

__device__ __forceinline__ float fdot2(h2_t a, h2_t b, float c) {
    return __builtin_amdgcn_fdot2(a, b, c, false);
}

__device__ __forceinline__ h2_t pack_h2(float x, float y) {
    return __builtin_amdgcn_cvt_pkrtz(x, y);
}

__device__ __forceinline__ float tanh_fast(float x) {
    float e = __expf(2.0f * x);
    return 1.0f - 2.0f * __builtin_amdgcn_rcpf(e + 1.0f);
}

// ---------------------------------------------------------------------------
// GEMM: block tile M=128 x N=64, K-chunk 32 (16 half2 pairs). 256 threads,
// each thread 8 rows x 4 cols, v_dot2_f32_f16 inner loop.
// ---------------------------------------------------------------------------
__global__ __launch_bounds__(256) void gemm_pre0(
    const float* __restrict__ x,    // [65536][768]
    const float* __restrict__ Wih,  // [64][768]
    const float* __restrict__ bih, const float* __restrict__ bhh,
    float* __restrict__ pre0)       // [65536][64]
{
    __shared__ h2_t As2[16][132];   // [k-pair][row]
    __shared__ h2_t Bs2[16][68];    // [k-pair][col]

    const int tid = threadIdx.x;
    const int tx = tid & 15;        // cols tx*4..+3
    const int ty = tid >> 4;        // rows ty*8..+7
    const int rowBase = blockIdx.x * 128;

    float acc[8][4];
#pragma unroll
    for (int r = 0; r < 8; ++r)
#pragma unroll
        for (int c = 0; c < 4; ++c) acc[r][c] = 0.0f;

    float4 aReg[4];   // A stage: 128 rows x 32 k / 256 thr (f32 in regs)
    float4 bReg[2];   // B stage: 64 rows x 32 k / 256 thr

#pragma unroll
    for (int jj = 0; jj < 4; ++jj) {
        int i = tid + 256 * jj;
        aReg[jj] = *(const float4*)&x[(size_t)(rowBase + (i >> 3)) * 768 + 4 * (i & 7)];
    }
#pragma unroll
    for (int jj = 0; jj < 2; ++jj) {
        int i = tid + 256 * jj;
        bReg[jj] = *(const float4*)&Wih[(i >> 3) * 768 + 4 * (i & 7)];
    }

    for (int c = 0; c < 24; ++c) {
        // stage regs -> LDS as half2 (k-pair major)
#pragma unroll
        for (int jj = 0; jj < 4; ++jj) {
            int i = tid + 256 * jj;
            int r = i >> 3, kp = 2 * (i & 7);
            As2[kp + 0][r] = pack_h2(aReg[jj].x, aReg[jj].y);
            As2[kp + 1][r] = pack_h2(aReg[jj].z, aReg[jj].w);
        }
#pragma unroll
        for (int jj = 0; jj < 2; ++jj) {
            int i = tid + 256 * jj;
            int h = i >> 3, kp = 2 * (i & 7);
            Bs2[kp + 0][h] = pack_h2(bReg[jj].x, bReg[jj].y);
            Bs2[kp + 1][h] = pack_h2(bReg[jj].z, bReg[jj].w);
        }
        __syncthreads();

        if (c + 1 < 24) {
            const int kb = (c + 1) * 32;
#pragma unroll
            for (int jj = 0; jj < 4; ++jj) {
                int i = tid + 256 * jj;
                aReg[jj] = *(const float4*)&x[(size_t)(rowBase + (i >> 3)) * 768 + kb + 4 * (i & 7)];
            }
#pragma unroll
            for (int jj = 0; jj < 2; ++jj) {
                int i = tid + 256 * jj;
                bReg[jj] = *(const float4*)&Wih[(i >> 3) * 768 + kb + 4 * (i & 7)];
            }
        }

#pragma unroll
        for (int kp = 0; kp < 16; ++kp) {
            F4H a0, a1, bv;
            a0.f = *(const float4*)&As2[kp][ty * 8];       // rows ty*8..+3
            a1.f = *(const float4*)&As2[kp][ty * 8 + 4];   // rows +4..+7
            bv.f = *(const float4*)&Bs2[kp][tx * 4];       // cols tx*4..+3
            h2_t ar[8] = {a0.h[0], a0.h[1], a0.h[2], a0.h[3],
                          a1.h[0], a1.h[1], a1.h[2], a1.h[3]};
#pragma unroll
            for (int r = 0; r < 8; ++r)
#pragma unroll
                for (int cc = 0; cc < 4; ++cc)
                    acc[r][cc] = fdot2(ar[r], bv.h[cc], acc[r][cc]);
        }
        __syncthreads();
    }

    float4 bias = make_float4(bih[tx * 4 + 0] + bhh[tx * 4 + 0],
                              bih[tx * 4 + 1] + bhh[tx * 4 + 1],
                              bih[tx * 4 + 2] + bhh[tx * 4 + 2],
                              bih[tx * 4 + 3] + bhh[tx * 4 + 3]);
#pragma unroll
    for (int r = 0; r < 8; ++r) {
        int row = rowBase + ty * 8 + r;
        float4 v = make_float4(acc[r][0] + bias.x, acc[r][1] + bias.y,
                               acc[r][2] + bias.z, acc[r][3] + bias.w);
        *(float4*)&pre0[(size_t)row * 64 + tx * 4] = v;
    }
}

// ---------------------------------------------------------------------------
// Recurrence: block = batch element, 3 waves (wave g = layer g at time t-g).
// Lane j owns output unit j; weights packed half2 in VGPRs (32+32 regs);
// h exchanged as f16 through LDS (8 b128 broadcast reads per vector).
// ---------------------------------------------------------------------------
__global__ __launch_bounds__(192, 1) void rnn_fused(
    const float* __restrict__ pre0,  // [128*512][64]
    const float* __restrict__ Whh0,
    const float* __restrict__ Wih1, const float* __restrict__ Whh1,
    const float* __restrict__ bih1, const float* __restrict__ bhh1,
    const float* __restrict__ Wih2, const float* __restrict__ Whh2,
    const float* __restrict__ bih2, const float* __restrict__ bhh2,
    const float* __restrict__ fcw, const float* __restrict__ fcb,
    float* __restrict__ out)
{
    const int tid = threadIdx.x;
    const int g   = tid >> 6;        // layer 0..2
    const int j   = tid & 63;        // output unit
    const int b   = blockIdx.x;

    __shared__ __align__(16) __fp16 hs[6][64];   // [2*layer + parity][unit]

    // packed weight rows (f16)
    const float* WA = (g == 0) ? Whh0 : ((g == 1) ? Wih1 : Wih2);
    const float* WB = (g == 0) ? Whh0 : ((g == 1) ? Whh1 : Whh2);  // g0: dummy
    h2_t wA2[32], wB2[32];
#pragma unroll
    for (int i = 0; i < 32; ++i) {
        wA2[i] = pack_h2(WA[j * 64 + 2 * i], WA[j * 64 + 2 * i + 1]);
        wB2[i] = pack_h2(WB[j * 64 + 2 * i], WB[j * 64 + 2 * i + 1]);
    }
    const float bias = (g == 0) ? 0.0f
                     : ((g == 1) ? (bih1[j] + bhh1[j]) : (bih2[j] + bhh2[j]));

    // zero all parity slots (h[-1] = 0): 6*64 halfs = 192 u32
    ((unsigned int*)hs)[tid] = 0u;

    // rolling pre0 prefetch for wave 0
    const size_t pbase = (size_t)b * 32768;
    float p0 = 0.f, p1 = 0.f;
    if (g == 0) {
        p0 = pre0[pbase + j];
        p1 = pre0[pbase + 64 + j];
    }
    __syncthreads();

    float hLast = 0.0f;

    for (int i = 0; i < 514; ++i) {
        if (g == 0) {
            if (i < 512) {
                const __fp16* rc = hs[(i + 1) & 1];   // h0[i-1]
                float a0 = 0.f, a1 = 0.f, a2 = 0.f, a3 = 0.f;
#pragma unroll
                for (int q = 0; q < 8; ++q) {
                    F4H u; u.f = *(const float4*)&rc[q * 8];
                    a0 = fdot2(wA2[q * 4 + 0], u.h[0], a0);
                    a1 = fdot2(wA2[q * 4 + 1], u.h[1], a1);
                    a2 = fdot2(wA2[q * 4 + 2], u.h[2], a2);
                    a3 = fdot2(wA2[q * 4 + 3], u.h[3], a3);
                }
                float hN = tanh_fast((a0 + a1) + (a2 + a3) + p0);
                hs[i & 1][j] = (__fp16)hN;
                p0 = p1;
                if (i + 2 < 512) p1 = pre0[pbase + (size_t)(i + 2) * 64 + j];
            }
        } else if (g == 1) {
            int t = i - 1;
            if (t >= 0 && t < 512) {
                const __fp16* inx = hs[t & 1];             // h0[t]
                const __fp16* rc  = hs[2 + ((t + 1) & 1)]; // h1[t-1]
                float a0 = 0.f, a1 = 0.f, a2 = 0.f, a3 = 0.f;
#pragma unroll
                for (int q = 0; q < 8; ++q) {
                    F4H ux, uh;
                    ux.f = *(const float4*)&inx[q * 8];
                    uh.f = *(const float4*)&rc[q * 8];
                    a0 = fdot2(wA2[q * 4 + 0], ux.h[0], a0);
                    a1 = fdot2(wA2[q * 4 + 1], ux.h[1], a1);
                    a2 = fdot2(wA2[q * 4 + 2], ux.h[2], a2);
                    a3 = fdot2(wA2[q * 4 + 3], ux.h[3], a3);
                    a0 = fdot2(wB2[q * 4 + 0], uh.h[0], a0);
                    a1 = fdot2(wB2[q * 4 + 1], uh.h[1], a1);
                    a2 = fdot2(wB2[q * 4 + 2], uh.h[2], a2);
                    a3 = fdot2(wB2[q * 4 + 3], uh.h[3], a3);
                }
                float hN = tanh_fast((a0 + a1) + (a2 + a3) + bias);
                hs[2 + (t & 1)][j] = (__fp16)hN;
            }
        } else {
            int t = i - 2;
            if (t >= 0 && t < 512) {
                const __fp16* inx = hs[2 + (t & 1)];       // h1[t]
                const __fp16* rc  = hs[4 + ((t + 1) & 1)]; // h2[t-1]
                float a0 = 0.f, a1 = 0.f, a2 = 0.f, a3 = 0.f;
#pragma unroll
                for (int q = 0; q < 8; ++q) {
                    F4H ux, uh;
                    ux.f = *(const float4*)&inx[q * 8];
                    uh.f = *(const float4*)&rc[q * 8];
                    a0 = fdot2(wA2[q * 4 + 0], ux.h[0], a0);
                    a1 = fdot2(wA2[q * 4 + 1], ux.h[1], a1);
                    a2 = fdot2(wA2[q * 4 + 2], ux.h[2], a2);
                    a3 = fdot2(wA2[q * 4 + 3], ux.h[3], a3);
                    a0 = fdot2(wB2[q * 4 + 0], uh.h[0], a0);
                    a1 = fdot2(wB2[q * 4 + 1], uh.h[1], a1);
                    a2 = fdot2(wB2[q * 4 + 2], uh.h[2], a2);
                    a3 = fdot2(wB2[q * 4 + 3], uh.h[3], a3);
                }
                float hN = tanh_fast((a0 + a1) + (a2 + a3) + bias);
                hs[4 + (t & 1)][j] = (__fp16)hN;
                if (t == 511) hLast = hN;
            }
        }
        __syncthreads();
    }

    // FC epilogue on wave 2 (holds h2[511] in hLast, fp32)
    if (g == 2) {
        float v = hLast * fcw[j];
#pragma unroll
        for (int m = 1; m < 64; m <<= 1) v += __shfl_xor(v, m, 64);
        if (j == 0) out[b] = v + fcb[0];
    }
}

extern "C" void kernel_launch(void* const* d_in, const int* in_sizes, int n_in,
                              void* d_out, int out_size, void* d_ws, size_t ws_size,
                              hipStream_t stream) {
    const float* x    = (const float*)d_in[0];
    const float* Wih0 = (const float*)d_in[2];
    const float* Whh0 = (const float*)d_in[3];
    const float* bih0 = (const float*)d_in[4];
    const float* bhh0 = (const float*)d_in[5];
    const float* Wih1 = (const float*)d_in[6];
    const float* Whh1 = (const float*)d_in[7];
    const float* bih1 = (const float*)d_in[8];
    const float* bhh1 = (const float*)d_in[9];
    const float* Wih2 = (const float*)d_in[10];
    const float* Whh2 = (const float*)d_in[11];
    const float* bih2 = (const float*)d_in[12];
    const float* bhh2 = (const float*)d_in[13];
    const float* fcw  = (const float*)d_in[14];
    const float* fcb  = (const float*)d_in[15];
    float* out  = (float*)d_out;
    float* pre0 = (float*)d_ws;   // 16.78 MB fp32

    gemm_pre0<<<512, 256, 0, stream>>>(x, Wih0, bih0, bhh0, pre0);
    rnn_fused<<<128, 192, 0, stream>>>(pre0, Whh0, Wih1, Whh1, bih1, bhh1,
                                       Wih2, Whh2, bih2, bhh2, fcw, fcb, out);
}

// Round 5
// 482.398 us; speedup vs baseline: 1.5387x; 1.1475x over previous
//
#include <hip/hip_runtime.h>

// ---------------------------------------------------------------------------
// RNNModel: 3-layer tanh RNN (B=128, T=512, IN=768, H=64) + FC(64->1)
// K1: MFMA f16 GEMM, LDS-free: wave = 32x64 C-tile, frags loaded straight
//     from global (A rows are fragment-shaped), 8 mfma_16x16x32_f16 / K-chunk.
// K2: fused recurrence, 3 waves (wave=layer), EPOCHED: 8 steps per barrier.
//     Own-layer recurrence uses intra-wave LDS ordering (lgkmcnt), no barrier.
// ---------------------------------------------------------------------------

typedef __fp16 h2_t __attribute__((ext_vector_type(2)));
typedef __fp16 h8_t __attribute__((ext_vector_type(8)));
typedef float  f4_t __attribute__((ext_vector_type(4)));

union F4H { float4 f; h2_t h[4]; };
union H8U { h2_t h2[4]; h8_t h8; };

__device__ __forceinline__ float fdot2(h2_t a, h2_t b, float c) {
    return __builtin_amdgcn_fdot2(a, b, c, false);
}
__device__ __forceinline__ h2_t pack_h2(float x, float y) {
    return __builtin_amdgcn_cvt_pkrtz(x, y);
}
__device__ __forceinline__ float tanh_fast(float x) {
    float e = __expf(2.0f * x);
    return 1.0f - 2.0f * __builtin_amdgcn_rcpf(e + 1.0f);
}

// ---------------------------------------------------------------------------
// GEMM: grid 512 x 256thr. Wave w owns rows blk*128 + w*32 .. +32, cols 0..64.
// A frag: lane holds x[row = m][k = q*8 + j] (8 consecutive floats -> cvt).
// B frag: lane holds W[n = m][k = q*8 + j]  (Wih is [64][768] row-major).
// C/D: col = lane&15, row = (lane>>4)*4 + reg.
// ---------------------------------------------------------------------------
__global__ __launch_bounds__(256) void gemm_pre0(
    const float* __restrict__ x,    // [65536][768]
    const float* __restrict__ Wih,  // [64][768]
    const float* __restrict__ bih, const float* __restrict__ bhh,
    float* __restrict__ pre0)       // [65536][64]
{
    const int tid = threadIdx.x;
    const int wv  = tid >> 6;
    const int l   = tid & 63;
    const int m   = l & 15;          // row/col within 16-tile
    const int q   = l >> 4;          // k-quad
    const int rowB = blockIdx.x * 128 + wv * 32;

    const float* ax0 = x + (size_t)(rowB + m) * 768 + q * 8;
    const float* ax1 = x + (size_t)(rowB + 16 + m) * 768 + q * 8;

    float4 ar[2][2];
    float4 br[4][2];

    // prologue: chunk 0
    ar[0][0] = *(const float4*)ax0;       ar[0][1] = *(const float4*)(ax0 + 4);
    ar[1][0] = *(const float4*)ax1;       ar[1][1] = *(const float4*)(ax1 + 4);
#pragma unroll
    for (int nt = 0; nt < 4; ++nt) {
        const float* p = Wih + (size_t)(nt * 16 + m) * 768 + q * 8;
        br[nt][0] = *(const float4*)p;    br[nt][1] = *(const float4*)(p + 4);
    }

    f4_t acc[2][4];
#pragma unroll
    for (int mt = 0; mt < 2; ++mt)
#pragma unroll
        for (int nt = 0; nt < 4; ++nt)
#pragma unroll
            for (int i = 0; i < 4; ++i) acc[mt][nt][i] = 0.0f;

#pragma unroll
    for (int it = 0; it < 24; ++it) {
        // convert current raw -> frags
        H8U fa[2], fb[4];
#pragma unroll
        for (int mt = 0; mt < 2; ++mt) {
            fa[mt].h2[0] = pack_h2(ar[mt][0].x, ar[mt][0].y);
            fa[mt].h2[1] = pack_h2(ar[mt][0].z, ar[mt][0].w);
            fa[mt].h2[2] = pack_h2(ar[mt][1].x, ar[mt][1].y);
            fa[mt].h2[3] = pack_h2(ar[mt][1].z, ar[mt][1].w);
        }
#pragma unroll
        for (int nt = 0; nt < 4; ++nt) {
            fb[nt].h2[0] = pack_h2(br[nt][0].x, br[nt][0].y);
            fb[nt].h2[1] = pack_h2(br[nt][0].z, br[nt][0].w);
            fb[nt].h2[2] = pack_h2(br[nt][1].x, br[nt][1].y);
            fb[nt].h2[3] = pack_h2(br[nt][1].z, br[nt][1].w);
        }
        // issue next chunk's loads (reg reads happen at cvt issue; safe WAR)
        if (it + 1 < 24) {
            const int ko = (it + 1) * 32;
            ar[0][0] = *(const float4*)(ax0 + ko);
            ar[0][1] = *(const float4*)(ax0 + ko + 4);
            ar[1][0] = *(const float4*)(ax1 + ko);
            ar[1][1] = *(const float4*)(ax1 + ko + 4);
#pragma unroll
            for (int nt = 0; nt < 4; ++nt) {
                const float* p = Wih + (size_t)(nt * 16 + m) * 768 + q * 8 + ko;
                br[nt][0] = *(const float4*)p;
                br[nt][1] = *(const float4*)(p + 4);
            }
        }
#pragma unroll
        for (int mt = 0; mt < 2; ++mt)
#pragma unroll
            for (int nt = 0; nt < 4; ++nt)
                acc[mt][nt] = __builtin_amdgcn_mfma_f32_16x16x32_f16(
                    fa[mt].h8, fb[nt].h8, acc[mt][nt], 0, 0, 0);
    }

    // epilogue: bias + store (col = nt*16 + m, row = rowB + mt*16 + q*4 + i)
    float bn[4];
#pragma unroll
    for (int nt = 0; nt < 4; ++nt) bn[nt] = bih[nt * 16 + m] + bhh[nt * 16 + m];
#pragma unroll
    for (int mt = 0; mt < 2; ++mt)
#pragma unroll
        for (int i = 0; i < 4; ++i) {
            int row = rowB + mt * 16 + q * 4 + i;
            float* pr = pre0 + (size_t)row * 64 + m;
#pragma unroll
            for (int nt = 0; nt < 4; ++nt)
                pr[nt * 16] = acc[mt][nt][i] + bn[nt];
        }
}

// ---------------------------------------------------------------------------
// Recurrence: block = batch element, 3 waves (wave g = layer g).
// Epochs of S=8 steps; ONE barrier per epoch. hb[layer][parity][slot][unit]:
// wave g writes slots of epoch e with parity e_g&1; consumer reads them
// next epoch (opposite parity) — WAR separated by exactly one barrier.
// ---------------------------------------------------------------------------
__global__ __launch_bounds__(192, 1) void rnn_fused(
    const float* __restrict__ pre0,  // [128*512][64], layer-0 biases folded in
    const float* __restrict__ Whh0,
    const float* __restrict__ Wih1, const float* __restrict__ Whh1,
    const float* __restrict__ bih1, const float* __restrict__ bhh1,
    const float* __restrict__ Wih2, const float* __restrict__ Whh2,
    const float* __restrict__ bih2, const float* __restrict__ bhh2,
    const float* __restrict__ fcw, const float* __restrict__ fcb,
    float* __restrict__ out)
{
    const int tid = threadIdx.x;
    const int g   = tid >> 6;        // layer 0..2
    const int j   = tid & 63;        // output unit
    const int b   = blockIdx.x;

    __shared__ __align__(16) __fp16 hb[3][2][8][64];

    // packed f16 weight rows in VGPRs
    const float* WA = (g == 0) ? Whh0 : ((g == 1) ? Wih1 : Wih2);
    const float* WB = (g == 0) ? Whh0 : ((g == 1) ? Whh1 : Whh2);  // g0: dummy
    h2_t wA2[32], wB2[32];
#pragma unroll
    for (int i = 0; i < 32; ++i) {
        wA2[i] = pack_h2(WA[j * 64 + 2 * i], WA[j * 64 + 2 * i + 1]);
        wB2[i] = pack_h2(WB[j * 64 + 2 * i], WB[j * 64 + 2 * i + 1]);
    }
    const float bias = (g == 0) ? 0.0f
                     : ((g == 1) ? (bih1[j] + bhh1[j]) : (bih2[j] + bhh2[j]));

    // zero all of hb: 3*2*8*64 f16 = 1536 dwords / 192 thr = 8 each
#pragma unroll
    for (int i = 0; i < 8; ++i) ((unsigned int*)hb)[tid + 192 * i] = 0u;

    // pre0 double-buffered epoch prefetch (wave 0)
    const size_t pbase = (size_t)b * 32768;
    float pc[8], pn[8];
    if (g == 0) {
#pragma unroll
        for (int s = 0; s < 8; ++s) pc[s] = pre0[pbase + s * 64 + j];
    }
    __syncthreads();

    float hLast = 0.0f;

    for (int e = 0; e < 66; ++e) {
        if (g == 0) {
            if (e < 64) {
                if (e < 63) {
#pragma unroll
                    for (int s = 0; s < 8; ++s)
                        pn[s] = pre0[pbase + (size_t)(e + 1) * 512 + s * 64 + j];
                }
                const int par = e & 1;
#pragma unroll
                for (int s = 0; s < 8; ++s) {
                    const __fp16* rc = (s == 0) ? hb[0][par ^ 1][7] : hb[0][par][s - 1];
                    float a0 = 0.f, a1 = 0.f, a2 = 0.f, a3 = 0.f;
#pragma unroll
                    for (int qq = 0; qq < 8; ++qq) {
                        F4H u; u.f = *(const float4*)&rc[qq * 8];
                        a0 = fdot2(wA2[qq * 4 + 0], u.h[0], a0);
                        a1 = fdot2(wA2[qq * 4 + 1], u.h[1], a1);
                        a2 = fdot2(wA2[qq * 4 + 2], u.h[2], a2);
                        a3 = fdot2(wA2[qq * 4 + 3], u.h[3], a3);
                    }
                    float hN = tanh_fast((a0 + a1) + (a2 + a3) + pc[s]);
                    hb[0][par][s][j] = (__fp16)hN;
                }
#pragma unroll
                for (int s = 0; s < 8; ++s) pc[s] = pn[s];
            }
        } else if (g == 1) {
            if (e >= 1 && e < 65) {
                const int par = (e - 1) & 1;
#pragma unroll
                for (int s = 0; s < 8; ++s) {
                    const __fp16* inx = hb[0][par][s];                       // h0[t]
                    const __fp16* rc  = (s == 0) ? hb[1][par ^ 1][7] : hb[1][par][s - 1];
                    float a0 = 0.f, a1 = 0.f, a2 = 0.f, a3 = 0.f;
#pragma unroll
                    for (int qq = 0; qq < 8; ++qq) {
                        F4H ux, uh;
                        ux.f = *(const float4*)&inx[qq * 8];
                        uh.f = *(const float4*)&rc[qq * 8];
                        a0 = fdot2(wA2[qq * 4 + 0], ux.h[0], a0);
                        a1 = fdot2(wA2[qq * 4 + 1], ux.h[1], a1);
                        a2 = fdot2(wA2[qq * 4 + 2], ux.h[2], a2);
                        a3 = fdot2(wA2[qq * 4 + 3], ux.h[3], a3);
                        a0 = fdot2(wB2[qq * 4 + 0], uh.h[0], a0);
                        a1 = fdot2(wB2[qq * 4 + 1], uh.h[1], a1);
                        a2 = fdot2(wB2[qq * 4 + 2], uh.h[2], a2);
                        a3 = fdot2(wB2[qq * 4 + 3], uh.h[3], a3);
                    }
                    float hN = tanh_fast((a0 + a1) + (a2 + a3) + bias);
                    hb[1][par][s][j] = (__fp16)hN;
                }
            }
        } else {
            if (e >= 2) {
                const int par = e & 1;   // == (e-2)&1
#pragma unroll
                for (int s = 0; s < 8; ++s) {
                    const __fp16* inx = hb[1][par][s];                       // h1[t]
                    const __fp16* rc  = (s == 0) ? hb[2][par ^ 1][7] : hb[2][par][s - 1];
                    float a0 = 0.f, a1 = 0.f, a2 = 0.f, a3 = 0.f;
#pragma unroll
                    for (int qq = 0; qq < 8; ++qq) {
                        F4H ux, uh;
                        ux.f = *(const float4*)&inx[qq * 8];
                        uh.f = *(const float4*)&rc[qq * 8];
                        a0 = fdot2(wA2[qq * 4 + 0], ux.h[0], a0);
                        a1 = fdot2(wA2[qq * 4 + 1], ux.h[1], a1);
                        a2 = fdot2(wA2[qq * 4 + 2], ux.h[2], a2);
                        a3 = fdot2(wA2[qq * 4 + 3], ux.h[3], a3);
                        a0 = fdot2(wB2[qq * 4 + 0], uh.h[0], a0);
                        a1 = fdot2(wB2[qq * 4 + 1], uh.h[1], a1);
                        a2 = fdot2(wB2[qq * 4 + 2], uh.h[2], a2);
                        a3 = fdot2(wB2[qq * 4 + 3], uh.h[3], a3);
                    }
                    float hN = tanh_fast((a0 + a1) + (a2 + a3) + bias);
                    hb[2][par][s][j] = (__fp16)hN;
                    if (e == 65 && s == 7) hLast = hN;   // t = 511
                }
            }
        }
        __syncthreads();
    }

    // FC epilogue on wave 2
    if (g == 2) {
        float v = hLast * fcw[j];
#pragma unroll
        for (int m = 1; m < 64; m <<= 1) v += __shfl_xor(v, m, 64);
        if (j == 0) out[b] = v + fcb[0];
    }
}

extern "C" void kernel_launch(void* const* d_in, const int* in_sizes, int n_in,
                              void* d_out, int out_size, void* d_ws, size_t ws_size,
                              hipStream_t stream) {
    const float* x    = (const float*)d_in[0];
    const float* Wih0 = (const float*)d_in[2];
    const float* Whh0 = (const float*)d_in[3];
    const float* bih0 = (const float*)d_in[4];
    const float* bhh0 = (const float*)d_in[5];
    const float* Wih1 = (const float*)d_in[6];
    const float* Whh1 = (const float*)d_in[7];
    const float* bih1 = (const float*)d_in[8];
    const float* bhh1 = (const float*)d_in[9];
    const float* Wih2 = (const float*)d_in[10];
    const float* Whh2 = (const float*)d_in[11];
    const float* bih2 = (const float*)d_in[12];
    const float* bhh2 = (const float*)d_in[13];
    const float* fcw  = (const float*)d_in[14];
    const float* fcb  = (const float*)d_in[15];
    float* out  = (float*)d_out;
    float* pre0 = (float*)d_ws;   // 16.78 MB fp32

    gemm_pre0<<<512, 256, 0, stream>>>(x, Wih0, bih0, bhh0, pre0);
    rnn_fused<<<128, 192, 0, stream>>>(pre0, Whh0, Wih1, Whh1, bih1, bhh1,
                                       Wih2, Whh2, bih2, bhh2, fcw, fcb, out);
}